// Round 11
// baseline (102.207 us; speedup 1.0000x reference)
//
#include <hip/hip_runtime.h>
#include <math.h>

// Problem constants (fixed by the reference setup)
constexpr int BB = 64, LL = 512, DD = 768, SS = 30;
constexpr int NDOMc = 5, NGATEc = 3, PRED = 2;

// Output layout (flat float32, reference return order)
constexpr size_t O_DOM   = 0;                               // (B,5)
constexpr size_t O_SPP   = O_DOM   + (size_t)BB*NDOMc;      // (B,30) sigmoid
constexpr size_t O_GATE  = O_SPP   + (size_t)BB*SS;         // (B,30,3) softmax
constexpr size_t O_SPTR  = O_GATE  + (size_t)BB*SS*NGATEc;  // (B,30) passthrough
constexpr size_t O_SGATE = O_SPTR  + (size_t)BB*SS;         // (B,30) passthrough
constexpr size_t O_SPROB = O_SGATE + (size_t)BB*SS;         // (B,30,512)
constexpr size_t O_EPROB = O_SPROB + (size_t)BB*SS*LL;      // (B,30,512)

// Workspace layout (floats): WgW[30*768*3], bgW[96], then ints
constexpr int WS_WGW = 0;
constexpr int WS_BGW = SS*DD*NGATEc;        // 69120
constexpr int WS_INT = WS_BGW + 96;         // 69216 (float offset where ints start)

constexpr int KB_ROWS = SS*DD + SS;         // 23070
constexpr int MAXW = 512;                   // max 4-slot items (64 * ceil(30/4))
constexpr int KBU  = (KB_ROWS + 7) / 8;     // 2884 kB units (8 rows each)
constexpr int KBG  = (KBU + 1) / 2;         // 1442 kB grabs (2 units each)
constexpr int NBLK = 1536;                  // persistent blocks (6/CU via 24KB LDS)

__device__ __forceinline__ float wred64(float v) {
    #pragma unroll
    for (int o = 32; o; o >>= 1) v += __shfl_xor(v, o);
    return v;
}

// ---------- Kernel A: per-batch small dots, passthrough, scan/compaction ----
__global__ __launch_bounds__(256) void kA(
    const float* __restrict__ cls, const float* __restrict__ Wdom,
    const float* __restrict__ bdom, const float* __restrict__ Wslot,
    const float* __restrict__ bslot, const int* __restrict__ sp,
    const int* __restrict__ sg, float* __restrict__ out,
    int* __restrict__ nptr, int* __restrict__ nsel,
    int* __restrict__ ptrpos, int* __restrict__ selpos)
{
    const int b = blockIdx.x;
    const int tid = threadIdx.x, lane = tid & 63, wid = tid >> 6;
    const float* c = cls + (size_t)b * DD;

    for (int t = wid; t < NDOMc + SS; t += 4) {
        float acc = 0.f;
        if (t < NDOMc) {
            for (int d = lane; d < DD; d += 64) acc += c[d] * Wdom[d*NDOMc + t];
        } else {
            const int j = t - NDOMc;
            for (int d = lane; d < DD; d += 64) acc += c[d] * Wslot[d*SS + j];
        }
        acc = wred64(acc);
        if (lane == 0) {
            if (t < NDOMc) out[O_DOM + (size_t)b*NDOMc + t] = acc + bdom[t];
            else {
                const int j = t - NDOMc;
                const float x = acc + bslot[j];
                out[O_SPP + (size_t)b*SS + j] = 1.f / (1.f + expf(-x));
            }
        }
    }
    if (tid < SS) {
        out[O_SPTR  + (size_t)b*SS + tid] = (float)sp[b*SS + tid];
        out[O_SGATE + (size_t)b*SS + tid] = (float)sg[b*SS + tid];
    }
    // serial scan: ptr ranks and pmask compaction.
    // NOTE: gate_at_slot = slot_gate[b, clip(csum-1,0,M-1)] -> indexed by RANK.
    if (tid == 0) {
        int cp = 0, cs = 0;
        for (int i = 0; i < SS; ++i) {
            if (sp[b*SS + i] == 1) {
                const int rank = cp;            // csum-1 at this position
                ptrpos[b*SS + rank] = i;
                ++cp;
                if (sg[b*SS + rank] == PRED) { selpos[b*SS + cs] = i; ++cs; }
            }
        }
        nptr[b] = cp; nsel[b] = cs;
    }
}

// ---------- Kernel A2: compact (b, 4-slot group) items; zero work counter ---
__global__ __launch_bounds__(64) void kA2(
    const int* __restrict__ nsel, int* __restrict__ items, int* __restrict__ NW,
    int* __restrict__ ctr)
{
    const int lane = threadIdx.x;               // 1 wave, lane == b
    const int ns = nsel[lane];
    const int cnt = (ns + 3) >> 2;              // ceil(ns/4) items
    int off = cnt;
    #pragma unroll
    for (int d = 1; d < 64; d <<= 1) {          // inclusive scan
        const int t = __shfl_up(off, d);
        if (lane >= d) off += t;
    }
    off -= cnt;                                 // exclusive prefix
    for (int i = 0; i < cnt; ++i) items[off + i] = lane * SS + 4*i;
    if (lane == 63) *NW = off + cnt;
    if (lane == 0) *ctr = 0;
}

// ---------- kBD: persistent blocks, atomic work-stealing --------------------
// Grab id g in [0, NW*8 + KBG):
//   g <  NW*8 : score grab = (item g>>3, chunk-pair g&7) -> 64 rows x <=4 slots,
//               weights staged ONCE in LDS, compute in 16-row register halves.
//   g >= NW*8 : kB grab = 2 units of 8 Wg rows (WgW precompute stream).
__global__ __launch_bounds__(256) void kBD(
    const float* __restrict__ H, const float* __restrict__ Ws,
    const float* __restrict__ We, const int* __restrict__ nsel,
    const int* __restrict__ selpos, float* __restrict__ out,
    const float* __restrict__ Wg, const float* __restrict__ bg,
    const float* __restrict__ Wgate,
    float* __restrict__ WgW, float* __restrict__ bgW,
    const int* __restrict__ items, const int* __restrict__ NW,
    int* __restrict__ ctr)
{
    __shared__ float4 wlds[1536];               // [slot 4][se 2][d4 192] = 24 KB
    __shared__ int sh_u;
    const int tid = threadIdx.x;
    const int lane = tid & 63, wid = tid >> 6;
    const int nsg = NW[0] * 8;                  // score grabs
    const int total = nsg + KBG;

    for (;;) {
        __syncthreads();                        // prev grab's LDS reads done
        if (tid == 0) sh_u = atomicAdd(ctr, 1);
        __syncthreads();
        const int u = sh_u;
        if (u >= total) return;

        if (u < nsg) {
            // ---- score grab -------------------------------------------------
            const int w = u >> 3, cp = u & 7;
            const int item = items[w];
            const int b = item / SS, k0 = item % SS;
            int tcnt = nsel[b] - k0; if (tcnt > 4) tcnt = 4;

            #pragma unroll
            for (int t6 = 0; t6 < 6; ++t6) {    // stage <=4 slots' Ws/We
                const int idx = t6*256 + tid;
                if (idx < tcnt*384) {
                    const int slot = idx / 384, rem = idx % 384;
                    const int se = rem / 192, d4 = rem % 192;
                    const int s = selpos[b*SS + k0 + slot];
                    const float4* src = (const float4*)((se ? We : Ws) + (size_t)s * DD);
                    wlds[idx] = src[d4];
                }
            }
            __syncthreads();

            const int grp = tid >> 4, m = tid & 15;
            #pragma unroll
            for (int hh = 0; hh < 4; ++hh) {    // 4 x 16 rows = 64 rows
                const int l = cp*64 + hh*16 + grp;
                const float4* h4 = (const float4*)(H + ((size_t)b * LL + l) * DD);
                float4 hr[12];
                #pragma unroll
                for (int j = 0; j < 12; ++j) hr[j] = h4[j*16 + m];
                for (int t = 0; t < tcnt; ++t) {
                    const float4* wls = wlds + t*384 + m;
                    float a = 0.f, e = 0.f;
                    #pragma unroll
                    for (int j = 0; j < 12; ++j) {
                        const float4 ww = wls[j*16];
                        const float4 uu = wls[192 + j*16];
                        a += hr[j].x*ww.x + hr[j].y*ww.y + hr[j].z*ww.z + hr[j].w*ww.w;
                        e += hr[j].x*uu.x + hr[j].y*uu.y + hr[j].z*uu.z + hr[j].w*uu.w;
                    }
                    #pragma unroll
                    for (int o = 8; o; o >>= 1) { a += __shfl_xor(a, o); e += __shfl_xor(e, o); }
                    if (m == 0) {
                        const int ka = k0 + t;
                        out[O_SPROB + (size_t)(b*SS + ka) * LL + l] = a;
                        out[O_EPROB + (size_t)(b*SS + ka) * LL + l] = e;
                    }
                }
            }
        } else {
            // ---- kB grab: 2 units x 8 rows of WgW precompute ----------------
            const int g = u - nsg;
            float wgt[3][4][3];
            #pragma unroll
            for (int j = 0; j < 3; ++j)
                #pragma unroll
                for (int cc = 0; cc < 4; ++cc) {
                    const int e = j*256 + lane*4 + cc;
                    #pragma unroll
                    for (int gg = 0; gg < NGATEc; ++gg) wgt[j][cc][gg] = Wgate[e*NGATEc + gg];
                }
            #pragma unroll
            for (int q = 0; q < 2; ++q) {
                const int x = g*2 + q;
                const int r0 = (x*4 + wid)*2;
                if (r0 >= KB_ROWS) continue;
                const float* src0 = (r0 < SS*DD) ? Wg + (size_t)r0*DD : bg + (size_t)(r0 - SS*DD)*DD;
                const int r1 = r0 + 1;
                const float* src1 = (r1 < SS*DD) ? Wg + (size_t)r1*DD : bg + (size_t)(r1 - SS*DD)*DD;
                float* dst0 = (r0 < SS*DD) ? WgW + (size_t)r0*3 : bgW + (r0 - SS*DD)*3;
                float* dst1 = (r1 < SS*DD) ? WgW + (size_t)r1*3 : bgW + (r1 - SS*DD)*3;

                const float4* s40 = (const float4*)src0;
                const float4* s41 = (const float4*)src1;
                float a0=0,a1=0,a2=0, c0=0,c1=0,c2=0;
                #pragma unroll
                for (int j = 0; j < 3; ++j) {
                    const float4 v  = s40[j*64 + lane];
                    const float4 w2 = s41[j*64 + lane];
                    a0 += v.x*wgt[j][0][0] + v.y*wgt[j][1][0] + v.z*wgt[j][2][0] + v.w*wgt[j][3][0];
                    a1 += v.x*wgt[j][0][1] + v.y*wgt[j][1][1] + v.z*wgt[j][2][1] + v.w*wgt[j][3][1];
                    a2 += v.x*wgt[j][0][2] + v.y*wgt[j][1][2] + v.z*wgt[j][2][2] + v.w*wgt[j][3][2];
                    c0 += w2.x*wgt[j][0][0] + w2.y*wgt[j][1][0] + w2.z*wgt[j][2][0] + w2.w*wgt[j][3][0];
                    c1 += w2.x*wgt[j][0][1] + w2.y*wgt[j][1][1] + w2.z*wgt[j][2][1] + w2.w*wgt[j][3][1];
                    c2 += w2.x*wgt[j][0][2] + w2.y*wgt[j][1][2] + w2.z*wgt[j][2][2] + w2.w*wgt[j][3][2];
                }
                a0 = wred64(a0); a1 = wred64(a1); a2 = wred64(a2);
                c0 = wred64(c0); c1 = wred64(c1); c2 = wred64(c2);
                if (lane == 0) {
                    dst0[0] = a0; dst0[1] = a1; dst0[2] = a2;
                    dst1[0] = c0; dst1[1] = c1; dst1[2] = c2;
                }
            }
        }
    }
}

// ---------- Kernel C: slot_gate_prob ----------------------------------------
__global__ __launch_bounds__(256) void kC(
    const float* __restrict__ cls, const float* __restrict__ WgW,
    const float* __restrict__ bgW, const float* __restrict__ bgate,
    const int* __restrict__ nptr, const int* __restrict__ ptrpos,
    float* __restrict__ out)
{
    const int lane = threadIdx.x & 63, wid = threadIdx.x >> 6;
    const int idx = blockIdx.x * 4 + wid;       // b*SS + m
    if (idx >= BB*SS) return;
    const int b = idx / SS, m = idx % SS;

    float s0, s1, s2;
    if (m < nptr[b]) {
        const int s = ptrpos[b*SS + m];
        const float4* c4 = (const float4*)(cls + (size_t)b * DD);
        float a0 = 0.f, a1 = 0.f, a2 = 0.f;
        #pragma unroll
        for (int j = 0; j < 3; ++j) {
            const float4 v = c4[j*64 + lane];
            const float* wp = WgW + ((size_t)s*DD + j*256 + lane*4) * 3;
            a0 += v.x*wp[0] + v.y*wp[3] + v.z*wp[6] + v.w*wp[9];
            a1 += v.x*wp[1] + v.y*wp[4] + v.z*wp[7] + v.w*wp[10];
            a2 += v.x*wp[2] + v.y*wp[5] + v.z*wp[8] + v.w*wp[11];
        }
        a0 = wred64(a0); a1 = wred64(a1); a2 = wred64(a2);
        s0 = a0 + bgW[s*3+0] + bgate[0];
        s1 = a1 + bgW[s*3+1] + bgate[1];
        s2 = a2 + bgW[s*3+2] + bgate[2];
    } else {
        s0 = bgate[0]; s1 = bgate[1]; s2 = bgate[2];
    }
    if (lane == 0) {
        const float mx = fmaxf(s0, fmaxf(s1, s2));
        const float e0 = expf(s0 - mx), e1 = expf(s1 - mx), e2 = expf(s2 - mx);
        const float inv = 1.f / (e0 + e1 + e2);
        float* o = out + O_GATE + (size_t)idx * NGATEc;
        o[0] = e0*inv; o[1] = e1*inv; o[2] = e2*inv;
    }
}

// ---------- Kernel E: softmax in place over L=512 ---------------------------
__global__ __launch_bounds__(256) void kE(
    const int* __restrict__ nsel, float* __restrict__ out)
{
    const int idx = blockIdx.x;             // b*SS + k
    const int b = idx / SS, k = idx % SS;
    const int tid = threadIdx.x;
    float* outs = out + O_SPROB + (size_t)idx * LL;
    float* oute = out + O_EPROB + (size_t)idx * LL;

    if (k >= nsel[b]) {                     // softmax(zeros) = 1/L exactly
        const float u = 1.0f / LL;
        outs[tid] = u; outs[tid + 256] = u;
        oute[tid] = u; oute[tid + 256] = u;
        return;
    }
    const int lane = tid & 63, wid = tid >> 6;
    __shared__ float rmax[2][4], rsum[2][4];

    const float s0 = outs[tid], s1 = outs[tid + 256];
    const float t0 = oute[tid], t1 = oute[tid + 256];

    float ms = fmaxf(s0, s1), me = fmaxf(t0, t1);
    #pragma unroll
    for (int o = 32; o; o >>= 1) { ms = fmaxf(ms, __shfl_xor(ms, o)); me = fmaxf(me, __shfl_xor(me, o)); }
    if (lane == 0) { rmax[0][wid] = ms; rmax[1][wid] = me; }
    __syncthreads();
    ms = fmaxf(fmaxf(rmax[0][0], rmax[0][1]), fmaxf(rmax[0][2], rmax[0][3]));
    me = fmaxf(fmaxf(rmax[1][0], rmax[1][1]), fmaxf(rmax[1][2], rmax[1][3]));

    const float e0 = expf(s0 - ms), e1 = expf(s1 - ms);
    const float f0 = expf(t0 - me), f1 = expf(t1 - me);
    float sa = e0 + e1, sb = f0 + f1;
    #pragma unroll
    for (int o = 32; o; o >>= 1) { sa += __shfl_xor(sa, o); sb += __shfl_xor(sb, o); }
    if (lane == 0) { rsum[0][wid] = sa; rsum[1][wid] = sb; }
    __syncthreads();
    const float inva = 1.f / (rsum[0][0] + rsum[0][1] + rsum[0][2] + rsum[0][3]);
    const float invb = 1.f / (rsum[1][0] + rsum[1][1] + rsum[1][2] + rsum[1][3]);

    outs[tid] = e0 * inva; outs[tid + 256] = e1 * inva;
    oute[tid] = f0 * invb; oute[tid + 256] = f1 * invb;
}

extern "C" void kernel_launch(void* const* d_in, const int* in_sizes, int n_in,
                              void* d_out, int out_size, void* d_ws, size_t ws_size,
                              hipStream_t stream)
{
    const float* H      = (const float*)d_in[0];
    const float* cls    = (const float*)d_in[1];
    const float* Wdom   = (const float*)d_in[2];
    const float* bdom   = (const float*)d_in[3];
    const float* Wslot  = (const float*)d_in[4];
    const float* bslot  = (const float*)d_in[5];
    const float* Wg     = (const float*)d_in[6];
    const float* bg     = (const float*)d_in[7];
    const float* Wgate  = (const float*)d_in[8];
    const float* bgate  = (const float*)d_in[9];
    const float* Wstart = (const float*)d_in[10];
    // d_in[11] b_start: constant per softmax row -> softmax-invariant, unused
    const float* Wend   = (const float*)d_in[12];
    // d_in[13] b_end: unused (same reason)
    const int* sp = (const int*)d_in[14];
    const int* sg = (const int*)d_in[15];

    float* out = (float*)d_out;
    float* wsf = (float*)d_ws;
    float* WgW = wsf + WS_WGW;
    float* bgW = wsf + WS_BGW;
    int* ipart  = (int*)(wsf + WS_INT);
    int* nptr   = ipart;
    int* nsel   = ipart + 64;
    int* ptrpos = ipart + 128;
    int* selpos = ptrpos + BB*SS;
    int* items  = selpos + BB*SS;
    int* NW     = items + MAXW;
    int* ctr    = NW + 1;

    kA<<<BB, 256, 0, stream>>>(cls, Wdom, bdom, Wslot, bslot, sp, sg, out,
                               nptr, nsel, ptrpos, selpos);
    kA2<<<1, 64, 0, stream>>>(nsel, items, NW, ctr);
    kBD<<<NBLK, 256, 0, stream>>>(H, Wstart, Wend, nsel, selpos, out,
                                  Wg, bg, Wgate, WgW, bgW, items, NW, ctr);
    kC<<<(BB*SS) / 4, 256, 0, stream>>>(cls, WgW, bgW, bgate, nptr, ptrpos, out);
    kE<<<BB * SS, 256, 0, stream>>>(nsel, out);
}

// Round 12
// 88.456 us; speedup vs baseline: 1.1555x; 1.1555x over previous
//
#include <hip/hip_runtime.h>
#include <math.h>

// Problem constants (fixed by the reference setup)
constexpr int BB = 64, LL = 512, DD = 768, SS = 30;
constexpr int NDOMc = 5, NGATEc = 3, PRED = 2;

// Output layout (flat float32, reference return order)
constexpr size_t O_DOM   = 0;                               // (B,5)
constexpr size_t O_SPP   = O_DOM   + (size_t)BB*NDOMc;      // (B,30) sigmoid
constexpr size_t O_GATE  = O_SPP   + (size_t)BB*SS;         // (B,30,3) softmax
constexpr size_t O_SPTR  = O_GATE  + (size_t)BB*SS*NGATEc;  // (B,30) passthrough
constexpr size_t O_SGATE = O_SPTR  + (size_t)BB*SS;         // (B,30) passthrough
constexpr size_t O_SPROB = O_SGATE + (size_t)BB*SS;         // (B,30,512)
constexpr size_t O_EPROB = O_SPROB + (size_t)BB*SS*LL;      // (B,30,512)

// Workspace layout (floats): WgW[30*768*3], bgW[96], then ints
constexpr int WS_WGW = 0;
constexpr int WS_BGW = SS*DD*NGATEc;        // 69120
constexpr int WS_INT = WS_BGW + 96;         // 69216 (float offset where ints start)

constexpr int KB_ROWS = SS*DD + SS;         // 23070
constexpr int KB_BLOCKS = (KB_ROWS/2 + 3) / 4;            // 2884
constexpr int KD_BLOCKS = BB * 32;                        // 2048 (b x 16-row chunk)

__device__ __forceinline__ float wred64(float v) {
    #pragma unroll
    for (int o = 32; o; o >>= 1) v += __shfl_xor(v, o);
    return v;
}

// ---------- Kernel A: per-batch small dots, passthrough, scan/compaction ----
__global__ __launch_bounds__(256) void kA(
    const float* __restrict__ cls, const float* __restrict__ Wdom,
    const float* __restrict__ bdom, const float* __restrict__ Wslot,
    const float* __restrict__ bslot, const int* __restrict__ sp,
    const int* __restrict__ sg, float* __restrict__ out,
    int* __restrict__ nptr, int* __restrict__ nsel,
    int* __restrict__ ptrpos, int* __restrict__ selpos)
{
    const int b = blockIdx.x;
    const int tid = threadIdx.x, lane = tid & 63, wid = tid >> 6;
    const float* c = cls + (size_t)b * DD;

    for (int t = wid; t < NDOMc + SS; t += 4) {
        float acc = 0.f;
        if (t < NDOMc) {
            for (int d = lane; d < DD; d += 64) acc += c[d] * Wdom[d*NDOMc + t];
        } else {
            const int j = t - NDOMc;
            for (int d = lane; d < DD; d += 64) acc += c[d] * Wslot[d*SS + j];
        }
        acc = wred64(acc);
        if (lane == 0) {
            if (t < NDOMc) out[O_DOM + (size_t)b*NDOMc + t] = acc + bdom[t];
            else {
                const int j = t - NDOMc;
                const float x = acc + bslot[j];
                out[O_SPP + (size_t)b*SS + j] = 1.f / (1.f + expf(-x));
            }
        }
    }
    if (tid < SS) {
        out[O_SPTR  + (size_t)b*SS + tid] = (float)sp[b*SS + tid];
        out[O_SGATE + (size_t)b*SS + tid] = (float)sg[b*SS + tid];
    }
    // serial scan: ptr ranks and pmask compaction.
    // NOTE: gate_at_slot = slot_gate[b, clip(csum-1,0,M-1)] -> indexed by RANK.
    // selpos padded with the last valid slot so kBD can stage UNCONDITIONALLY.
    if (tid == 0) {
        int cp = 0, cs = 0;
        for (int i = 0; i < SS; ++i) {
            if (sp[b*SS + i] == 1) {
                const int rank = cp;            // csum-1 at this position
                ptrpos[b*SS + rank] = i;
                ++cp;
                if (sg[b*SS + rank] == PRED) { selpos[b*SS + cs] = i; ++cs; }
            }
        }
        nptr[b] = cp; nsel[b] = cs;
        const int last = (cs > 0) ? selpos[b*SS + cs - 1] : 0;
        for (int i = cs; i < SS; ++i) selpos[b*SS + i] = last;
    }
}

// ---------- fused kBD: kB blocks first, then (b, 16-row chunk) score blocks -
__global__ __launch_bounds__(256, 3) void kBD(
    const float* __restrict__ H, const float* __restrict__ Ws,
    const float* __restrict__ We, const int* __restrict__ nsel,
    const int* __restrict__ selpos, float* __restrict__ out,
    const float* __restrict__ Wg, const float* __restrict__ bg,
    const float* __restrict__ Wgate,
    float* __restrict__ WgW, float* __restrict__ bgW)
{
    __shared__ float4 wlds[1536];               // [slot 4][se 2][d4 192] = 24 KB
    const int bid = blockIdx.x;
    const int tid = threadIdx.x;

    if (bid >= KB_BLOCKS) {
        // ---- scores: block = (b, 16-row chunk); all ns slots in rounds of 4.
        // H rows in registers ONCE (statically indexed, no conditional defs).
        const int bidd = bid - KB_BLOCKS;
        const int b = bidd & 63;                    // batch minor: spreads b
        const int c = bidd >> 6;                    // chunk (16 rows)
        const int ns = nsel[b];
        if (ns == 0) return;                        // kE fills uniform rows
        const int R = (ns + 3) >> 2;                // rounds

        const int grp = tid >> 4, m = tid & 15;     // 16 groups x 16 lanes
        const int l = c * 16 + grp;                 // this group's row

        const float4* h4 = (const float4*)(H + ((size_t)b * LL + l) * DD);
        float4 hr[12];
        #pragma unroll
        for (int j = 0; j < 12; ++j) hr[j] = h4[j*16 + m];

        for (int r = 0; r < R; ++r) {
            if (r) __syncthreads();                 // prev round's LDS reads done
            // stage 4 slots unconditionally (selpos padded by kA)
            #pragma unroll
            for (int t6 = 0; t6 < 6; ++t6) {
                const int idx = t6*256 + tid;       // 0..1535
                const int slot = idx / 384, rem = idx % 384;
                const int se = rem / 192, d4 = rem % 192;
                int kk = 4*r + slot; if (kk > SS-1) kk = SS-1;
                const int s = selpos[b*SS + kk];
                const float4* src = (const float4*)((se ? We : Ws) + (size_t)s * DD);
                wlds[idx] = src[d4];
            }
            __syncthreads();

            #pragma unroll
            for (int t = 0; t < 4; ++t) {
                const float4* wls = wlds + t*384 + m;
                float a = 0.f, e = 0.f;
                #pragma unroll
                for (int j = 0; j < 12; ++j) {
                    const float4 ww = wls[j*16];
                    const float4 uu = wls[192 + j*16];
                    a += hr[j].x*ww.x + hr[j].y*ww.y + hr[j].z*ww.z + hr[j].w*ww.w;
                    e += hr[j].x*uu.x + hr[j].y*uu.y + hr[j].z*uu.z + hr[j].w*uu.w;
                }
                #pragma unroll
                for (int o = 8; o; o >>= 1) { a += __shfl_xor(a, o); e += __shfl_xor(e, o); }
                const int ka = 4*r + t;
                if (m == 0 && ka < ns) {
                    out[O_SPROB + (size_t)(b*SS + ka) * LL + l] = a;
                    out[O_EPROB + (size_t)(b*SS + ka) * LL + l] = e;
                }
            }
        }
        return;
    }

    // ---- WgW precompute (bid < KB_BLOCKS): 2 rows per wave; pure HBM stream -
    const int lane = tid & 63, wid = tid >> 6;
    const int r0 = (bid * 4 + wid) * 2;
    if (r0 >= KB_ROWS) return;

    float wgt[3][4][3];
    #pragma unroll
    for (int j = 0; j < 3; ++j)
        #pragma unroll
        for (int cc = 0; cc < 4; ++cc) {
            const int e = j*256 + lane*4 + cc;
            #pragma unroll
            for (int g = 0; g < NGATEc; ++g) wgt[j][cc][g] = Wgate[e*NGATEc + g];
        }

    const float* src0 = (r0 < SS*DD) ? Wg + (size_t)r0*DD : bg + (size_t)(r0 - SS*DD)*DD;
    const int r1 = r0 + 1;
    const float* src1 = (r1 < SS*DD) ? Wg + (size_t)r1*DD : bg + (size_t)(r1 - SS*DD)*DD;
    float* dst0 = (r0 < SS*DD) ? WgW + (size_t)r0*3 : bgW + (r0 - SS*DD)*3;
    float* dst1 = (r1 < SS*DD) ? WgW + (size_t)r1*3 : bgW + (r1 - SS*DD)*3;

    const float4* s40 = (const float4*)src0;
    const float4* s41 = (const float4*)src1;
    float a0=0,a1=0,a2=0, c0=0,c1=0,c2=0;
    #pragma unroll
    for (int j = 0; j < 3; ++j) {
        const float4 v  = s40[j*64 + lane];
        const float4 w2 = s41[j*64 + lane];
        a0 += v.x*wgt[j][0][0] + v.y*wgt[j][1][0] + v.z*wgt[j][2][0] + v.w*wgt[j][3][0];
        a1 += v.x*wgt[j][0][1] + v.y*wgt[j][1][1] + v.z*wgt[j][2][1] + v.w*wgt[j][3][1];
        a2 += v.x*wgt[j][0][2] + v.y*wgt[j][1][2] + v.z*wgt[j][2][2] + v.w*wgt[j][3][2];
        c0 += w2.x*wgt[j][0][0] + w2.y*wgt[j][1][0] + w2.z*wgt[j][2][0] + w2.w*wgt[j][3][0];
        c1 += w2.x*wgt[j][0][1] + w2.y*wgt[j][1][1] + w2.z*wgt[j][2][1] + w2.w*wgt[j][3][1];
        c2 += w2.x*wgt[j][0][2] + w2.y*wgt[j][1][2] + w2.z*wgt[j][2][2] + w2.w*wgt[j][3][2];
    }
    a0 = wred64(a0); a1 = wred64(a1); a2 = wred64(a2);
    c0 = wred64(c0); c1 = wred64(c1); c2 = wred64(c2);
    if (lane == 0) {
        dst0[0] = a0; dst0[1] = a1; dst0[2] = a2;
        dst1[0] = c0; dst1[1] = c1; dst1[2] = c2;
    }
}

// ---------- Kernel C: slot_gate_prob ----------------------------------------
__global__ __launch_bounds__(256) void kC(
    const float* __restrict__ cls, const float* __restrict__ WgW,
    const float* __restrict__ bgW, const float* __restrict__ bgate,
    const int* __restrict__ nptr, const int* __restrict__ ptrpos,
    float* __restrict__ out)
{
    const int lane = threadIdx.x & 63, wid = threadIdx.x >> 6;
    const int idx = blockIdx.x * 4 + wid;       // b*SS + m
    if (idx >= BB*SS) return;
    const int b = idx / SS, m = idx % SS;

    float s0, s1, s2;
    if (m < nptr[b]) {
        const int s = ptrpos[b*SS + m];
        const float4* c4 = (const float4*)(cls + (size_t)b * DD);
        float a0 = 0.f, a1 = 0.f, a2 = 0.f;
        #pragma unroll
        for (int j = 0; j < 3; ++j) {
            const float4 v = c4[j*64 + lane];
            const float* wp = WgW + ((size_t)s*DD + j*256 + lane*4) * 3;
            a0 += v.x*wp[0] + v.y*wp[3] + v.z*wp[6] + v.w*wp[9];
            a1 += v.x*wp[1] + v.y*wp[4] + v.z*wp[7] + v.w*wp[10];
            a2 += v.x*wp[2] + v.y*wp[5] + v.z*wp[8] + v.w*wp[11];
        }
        a0 = wred64(a0); a1 = wred64(a1); a2 = wred64(a2);
        s0 = a0 + bgW[s*3+0] + bgate[0];
        s1 = a1 + bgW[s*3+1] + bgate[1];
        s2 = a2 + bgW[s*3+2] + bgate[2];
    } else {
        s0 = bgate[0]; s1 = bgate[1]; s2 = bgate[2];
    }
    if (lane == 0) {
        const float mx = fmaxf(s0, fmaxf(s1, s2));
        const float e0 = expf(s0 - mx), e1 = expf(s1 - mx), e2 = expf(s2 - mx);
        const float inv = 1.f / (e0 + e1 + e2);
        float* o = out + O_GATE + (size_t)idx * NGATEc;
        o[0] = e0*inv; o[1] = e1*inv; o[2] = e2*inv;
    }
}

// ---------- Kernel E: softmax in place over L=512 ---------------------------
__global__ __launch_bounds__(256) void kE(
    const int* __restrict__ nsel, float* __restrict__ out)
{
    const int idx = blockIdx.x;             // b*SS + k
    const int b = idx / SS, k = idx % SS;
    const int tid = threadIdx.x;
    float* outs = out + O_SPROB + (size_t)idx * LL;
    float* oute = out + O_EPROB + (size_t)idx * LL;

    if (k >= nsel[b]) {                     // softmax(zeros) = 1/L exactly
        const float u = 1.0f / LL;
        outs[tid] = u; outs[tid + 256] = u;
        oute[tid] = u; oute[tid + 256] = u;
        return;
    }
    const int lane = tid & 63, wid = tid >> 6;
    __shared__ float rmax[2][4], rsum[2][4];

    const float s0 = outs[tid], s1 = outs[tid + 256];
    const float t0 = oute[tid], t1 = oute[tid + 256];

    float ms = fmaxf(s0, s1), me = fmaxf(t0, t1);
    #pragma unroll
    for (int o = 32; o; o >>= 1) { ms = fmaxf(ms, __shfl_xor(ms, o)); me = fmaxf(me, __shfl_xor(me, o)); }
    if (lane == 0) { rmax[0][wid] = ms; rmax[1][wid] = me; }
    __syncthreads();
    ms = fmaxf(fmaxf(rmax[0][0], rmax[0][1]), fmaxf(rmax[0][2], rmax[0][3]));
    me = fmaxf(fmaxf(rmax[1][0], rmax[1][1]), fmaxf(rmax[1][2], rmax[1][3]));

    const float e0 = expf(s0 - ms), e1 = expf(s1 - ms);
    const float f0 = expf(t0 - me), f1 = expf(t1 - me);
    float sa = e0 + e1, sb = f0 + f1;
    #pragma unroll
    for (int o = 32; o; o >>= 1) { sa += __shfl_xor(sa, o); sb += __shfl_xor(sb, o); }
    if (lane == 0) { rsum[0][wid] = sa; rsum[1][wid] = sb; }
    __syncthreads();
    const float inva = 1.f / (rsum[0][0] + rsum[0][1] + rsum[0][2] + rsum[0][3]);
    const float invb = 1.f / (rsum[1][0] + rsum[1][1] + rsum[1][2] + rsum[1][3]);

    outs[tid] = e0 * inva; outs[tid + 256] = e1 * inva;
    oute[tid] = f0 * invb; oute[tid + 256] = f1 * invb;
}

extern "C" void kernel_launch(void* const* d_in, const int* in_sizes, int n_in,
                              void* d_out, int out_size, void* d_ws, size_t ws_size,
                              hipStream_t stream)
{
    const float* H      = (const float*)d_in[0];
    const float* cls    = (const float*)d_in[1];
    const float* Wdom   = (const float*)d_in[2];
    const float* bdom   = (const float*)d_in[3];
    const float* Wslot  = (const float*)d_in[4];
    const float* bslot  = (const float*)d_in[5];
    const float* Wg     = (const float*)d_in[6];
    const float* bg     = (const float*)d_in[7];
    const float* Wgate  = (const float*)d_in[8];
    const float* bgate  = (const float*)d_in[9];
    const float* Wstart = (const float*)d_in[10];
    // d_in[11] b_start: constant per softmax row -> softmax-invariant, unused
    const float* Wend   = (const float*)d_in[12];
    // d_in[13] b_end: unused (same reason)
    const int* sp = (const int*)d_in[14];
    const int* sg = (const int*)d_in[15];

    float* out = (float*)d_out;
    float* wsf = (float*)d_ws;
    float* WgW = wsf + WS_WGW;
    float* bgW = wsf + WS_BGW;
    int* ipart  = (int*)(wsf + WS_INT);
    int* nptr   = ipart;
    int* nsel   = ipart + 64;
    int* ptrpos = ipart + 128;
    int* selpos = ptrpos + BB*SS;

    kA<<<BB, 256, 0, stream>>>(cls, Wdom, bdom, Wslot, bslot, sp, sg, out,
                               nptr, nsel, ptrpos, selpos);
    kBD<<<KB_BLOCKS + KD_BLOCKS, 256, 0, stream>>>(H, Wstart, Wend, nsel, selpos, out,
                                                   Wg, bg, Wgate, WgW, bgW);
    kC<<<(BB*SS) / 4, 256, 0, stream>>>(cls, WgW, bgW, bgate, nptr, ptrpos, out);
    kE<<<BB * SS, 256, 0, stream>>>(nsel, out);
}

// Round 13
// 79.583 us; speedup vs baseline: 1.2843x; 1.1115x over previous
//
#include <hip/hip_runtime.h>
#include <math.h>

// Problem constants (fixed by the reference setup)
constexpr int BB = 64, LL = 512, DD = 768, SS = 30;
constexpr int NDOMc = 5, NGATEc = 3, PRED = 2;

// Output layout (flat float32, reference return order)
constexpr size_t O_DOM   = 0;                               // (B,5)
constexpr size_t O_SPP   = O_DOM   + (size_t)BB*NDOMc;      // (B,30) sigmoid
constexpr size_t O_GATE  = O_SPP   + (size_t)BB*SS;         // (B,30,3) softmax
constexpr size_t O_SPTR  = O_GATE  + (size_t)BB*SS*NGATEc;  // (B,30) passthrough
constexpr size_t O_SGATE = O_SPTR  + (size_t)BB*SS;         // (B,30) passthrough
constexpr size_t O_SPROB = O_SGATE + (size_t)BB*SS;         // (B,30,512)
constexpr size_t O_EPROB = O_SPROB + (size_t)BB*SS*LL;      // (B,30,512)

// Workspace layout (floats): WgW[30*768*3], bgW[96], then ints
constexpr int WS_WGW = 0;
constexpr int WS_BGW = SS*DD*NGATEc;        // 69120
constexpr int WS_INT = WS_BGW + 96;         // 69216 (float offset where ints start)

constexpr int KB_ROWS = SS*DD + SS;         // 23070
constexpr int MAXW = 512;                   // max 4-slot items
constexpr int SCORE_BLOCKS = MAXW * 16;     // wait -- 512*16 = 8192? no: see below
// Score block = (item w, chunk c of 32 rows): 16 chunks; grid sized for 256 items.
constexpr int SBLK = 256 * 16;              // 4096 score slots (items <= 256 in practice)
constexpr int KB_BLOCKS = (KB_ROWS/2 + 3) / 4;            // 2884
// Interleave: per 12 consecutive bids, 7 score + 5 kB.
constexpr int NGRP = (SBLK + 6) / 7 > (KB_BLOCKS + 4) / 5 ? (SBLK + 6) / 7 : (KB_BLOCKS + 4) / 5;  // 586
constexpr int GRID_BD = NGRP * 12;          // 7032

__device__ __forceinline__ float wred64(float v) {
    #pragma unroll
    for (int o = 32; o; o >>= 1) v += __shfl_xor(v, o);
    return v;
}

// ---------- Kernel A: per-batch small dots, passthrough, scan/compaction ----
__global__ __launch_bounds__(256) void kA(
    const float* __restrict__ cls, const float* __restrict__ Wdom,
    const float* __restrict__ bdom, const float* __restrict__ Wslot,
    const float* __restrict__ bslot, const int* __restrict__ sp,
    const int* __restrict__ sg, float* __restrict__ out,
    int* __restrict__ nptr, int* __restrict__ nsel,
    int* __restrict__ ptrpos, int* __restrict__ selpos)
{
    const int b = blockIdx.x;
    const int tid = threadIdx.x, lane = tid & 63, wid = tid >> 6;
    const float* c = cls + (size_t)b * DD;

    for (int t = wid; t < NDOMc + SS; t += 4) {
        float acc = 0.f;
        if (t < NDOMc) {
            for (int d = lane; d < DD; d += 64) acc += c[d] * Wdom[d*NDOMc + t];
        } else {
            const int j = t - NDOMc;
            for (int d = lane; d < DD; d += 64) acc += c[d] * Wslot[d*SS + j];
        }
        acc = wred64(acc);
        if (lane == 0) {
            if (t < NDOMc) out[O_DOM + (size_t)b*NDOMc + t] = acc + bdom[t];
            else {
                const int j = t - NDOMc;
                const float x = acc + bslot[j];
                out[O_SPP + (size_t)b*SS + j] = 1.f / (1.f + expf(-x));
            }
        }
    }
    if (tid < SS) {
        out[O_SPTR  + (size_t)b*SS + tid] = (float)sp[b*SS + tid];
        out[O_SGATE + (size_t)b*SS + tid] = (float)sg[b*SS + tid];
    }
    // serial scan: ptr ranks and pmask compaction.
    // NOTE: gate_at_slot = slot_gate[b, clip(csum-1,0,M-1)] -> indexed by RANK.
    // selpos padded with the last valid slot so kBD stages UNCONDITIONALLY.
    if (tid == 0) {
        int cp = 0, cs = 0;
        for (int i = 0; i < SS; ++i) {
            if (sp[b*SS + i] == 1) {
                const int rank = cp;            // csum-1 at this position
                ptrpos[b*SS + rank] = i;
                ++cp;
                if (sg[b*SS + rank] == PRED) { selpos[b*SS + cs] = i; ++cs; }
            }
        }
        nptr[b] = cp; nsel[b] = cs;
        const int last = (cs > 0) ? selpos[b*SS + cs - 1] : 0;
        for (int i = cs; i < SS; ++i) selpos[b*SS + i] = last;
    }
}

// ---------- Kernel A2: compact (b, 4-slot group) work items, sorted by b ----
__global__ __launch_bounds__(64) void kA2(
    const int* __restrict__ nsel, int* __restrict__ items, int* __restrict__ NW)
{
    const int lane = threadIdx.x;               // 1 wave, lane == b
    const int ns = nsel[lane];
    const int cnt = (ns + 3) >> 2;              // ceil(ns/4) items
    int off = cnt;
    #pragma unroll
    for (int d = 1; d < 64; d <<= 1) {          // inclusive scan
        const int t = __shfl_up(off, d);
        if (lane >= d) off += t;
    }
    off -= cnt;                                 // exclusive prefix
    for (int i = 0; i < cnt; ++i) items[off + i] = lane * SS + 4*i;
    if (lane == 63) *NW = off + cnt;
}

// ---------- fused kBD: kB and score blocks INTERLEAVED (5:7 per 12) ---------
__global__ __launch_bounds__(256, 2) void kBD(
    const float* __restrict__ H, const float* __restrict__ Ws,
    const float* __restrict__ We, const int* __restrict__ nsel,
    const int* __restrict__ selpos, float* __restrict__ out,
    const float* __restrict__ Wg, const float* __restrict__ bg,
    const float* __restrict__ Wgate,
    float* __restrict__ WgW, float* __restrict__ bgW,
    const int* __restrict__ items, const int* __restrict__ NW)
{
    __shared__ float4 wlds[1536];               // [slot 4][se 2][d4 192] = 24 KB
    const int bid = blockIdx.x;
    const int tid = threadIdx.x;
    const int g12 = bid / 12, r12 = bid % 12;

    if (r12 < 7) {
        // ---- score block: item w (4 slots) x 32 rows; 2 rows per 16-lane grp
        const int sb = g12 * 7 + r12;
        if (sb >= SBLK) return;
        const int w = sb >> 4, c = sb & 15;
        if (w >= *NW) return;
        const int item = items[w];
        const int b = item / SS, k0 = item % SS;
        const int ns = nsel[b];
        int tcnt = ns - k0; if (tcnt > 4) tcnt = 4;

        const int grp = tid >> 4, m = tid & 15;     // 16 groups x 16 lanes
        const int l0 = c * 32 + grp;                // rows l0, l0+16
        const int l1 = l0 + 16;

        // H rows -> registers FIRST (latency hides under W staging below)
        const float4* h40 = (const float4*)(H + ((size_t)b * LL + l0) * DD);
        const float4* h41 = (const float4*)(H + ((size_t)b * LL + l1) * DD);
        float4 hr0[12], hr1[12];
        #pragma unroll
        for (int j = 0; j < 12; ++j) { hr0[j] = h40[j*16 + m]; hr1[j] = h41[j*16 + m]; }
        // pin to VGPRs: forbid rematerialization (per-slot H re-reads)
        #pragma unroll
        for (int j = 0; j < 12; ++j) {
            asm volatile("" : "+v"(hr0[j].x), "+v"(hr0[j].y), "+v"(hr0[j].z), "+v"(hr0[j].w));
            asm volatile("" : "+v"(hr1[j].x), "+v"(hr1[j].y), "+v"(hr1[j].z), "+v"(hr1[j].w));
        }

        // stage 4 slots' W_start/W_end unconditionally (selpos padded by kA)
        #pragma unroll
        for (int t6 = 0; t6 < 6; ++t6) {
            const int idx = t6*256 + tid;           // 0..1535
            const int slot = idx / 384, rem = idx % 384;
            const int se = rem / 192, d4 = rem % 192;
            int kk = k0 + slot; if (kk > SS-1) kk = SS-1;
            const int s = selpos[b*SS + kk];
            const float4* src = (const float4*)((se ? We : Ws) + (size_t)s * DD);
            wlds[idx] = src[d4];
        }
        __syncthreads();

        for (int t = 0; t < tcnt; ++t) {            // valid slots only
            const float4* wls = wlds + t*384 + m;
            float a0=0.f, a1=0.f, e0=0.f, e1=0.f;
            #pragma unroll
            for (int j = 0; j < 12; ++j) {          // 2 ds_read_b128 : 16 fma
                const float4 ww = wls[j*16];
                const float4 uu = wls[192 + j*16];
                a0 += hr0[j].x*ww.x + hr0[j].y*ww.y + hr0[j].z*ww.z + hr0[j].w*ww.w;
                a1 += hr1[j].x*ww.x + hr1[j].y*ww.y + hr1[j].z*ww.z + hr1[j].w*ww.w;
                e0 += hr0[j].x*uu.x + hr0[j].y*uu.y + hr0[j].z*uu.z + hr0[j].w*uu.w;
                e1 += hr1[j].x*uu.x + hr1[j].y*uu.y + hr1[j].z*uu.z + hr1[j].w*uu.w;
            }
            #pragma unroll
            for (int o = 8; o; o >>= 1) {
                a0 += __shfl_xor(a0, o); a1 += __shfl_xor(a1, o);
                e0 += __shfl_xor(e0, o); e1 += __shfl_xor(e1, o);
            }
            if (m == 0) {
                const int ka = k0 + t;
                out[O_SPROB + (size_t)(b*SS + ka) * LL + l0] = a0;
                out[O_SPROB + (size_t)(b*SS + ka) * LL + l1] = a1;
                out[O_EPROB + (size_t)(b*SS + ka) * LL + l0] = e0;
                out[O_EPROB + (size_t)(b*SS + ka) * LL + l1] = e1;
            }
        }
        return;
    }

    // ---- kB block: WgW precompute, 2 rows per wave; pure HBM stream --------
    const int kb = g12 * 5 + (r12 - 7);
    if (kb >= (KB_ROWS/2 + 3) / 4) return;
    const int lane = tid & 63, wid = tid >> 6;
    const int r0 = (kb * 4 + wid) * 2;
    if (r0 >= KB_ROWS) return;

    float wgt[3][4][3];
    #pragma unroll
    for (int j = 0; j < 3; ++j)
        #pragma unroll
        for (int cc = 0; cc < 4; ++cc) {
            const int e = j*256 + lane*4 + cc;
            #pragma unroll
            for (int gg = 0; gg < NGATEc; ++gg) wgt[j][cc][gg] = Wgate[e*NGATEc + gg];
        }

    const float* src0 = (r0 < SS*DD) ? Wg + (size_t)r0*DD : bg + (size_t)(r0 - SS*DD)*DD;
    const int r1 = r0 + 1;
    const float* src1 = (r1 < SS*DD) ? Wg + (size_t)r1*DD : bg + (size_t)(r1 - SS*DD)*DD;
    float* dst0 = (r0 < SS*DD) ? WgW + (size_t)r0*3 : bgW + (r0 - SS*DD)*3;
    float* dst1 = (r1 < SS*DD) ? WgW + (size_t)r1*3 : bgW + (r1 - SS*DD)*3;

    const float4* s40 = (const float4*)src0;
    const float4* s41 = (const float4*)src1;
    float a0=0,a1=0,a2=0, c0=0,c1=0,c2=0;
    #pragma unroll
    for (int j = 0; j < 3; ++j) {
        const float4 v  = s40[j*64 + lane];
        const float4 w2 = s41[j*64 + lane];
        a0 += v.x*wgt[j][0][0] + v.y*wgt[j][1][0] + v.z*wgt[j][2][0] + v.w*wgt[j][3][0];
        a1 += v.x*wgt[j][0][1] + v.y*wgt[j][1][1] + v.z*wgt[j][2][1] + v.w*wgt[j][3][1];
        a2 += v.x*wgt[j][0][2] + v.y*wgt[j][1][2] + v.z*wgt[j][2][2] + v.w*wgt[j][3][2];
        c0 += w2.x*wgt[j][0][0] + w2.y*wgt[j][1][0] + w2.z*wgt[j][2][0] + w2.w*wgt[j][3][0];
        c1 += w2.x*wgt[j][0][1] + w2.y*wgt[j][1][1] + w2.z*wgt[j][2][1] + w2.w*wgt[j][3][1];
        c2 += w2.x*wgt[j][0][2] + w2.y*wgt[j][1][2] + w2.z*wgt[j][2][2] + w2.w*wgt[j][3][2];
    }
    a0 = wred64(a0); a1 = wred64(a1); a2 = wred64(a2);
    c0 = wred64(c0); c1 = wred64(c1); c2 = wred64(c2);
    if (lane == 0) {
        dst0[0] = a0; dst0[1] = a1; dst0[2] = a2;
        dst1[0] = c0; dst1[1] = c1; dst1[2] = c2;
    }
}

// ---------- Kernel C: slot_gate_prob ----------------------------------------
__global__ __launch_bounds__(256) void kC(
    const float* __restrict__ cls, const float* __restrict__ WgW,
    const float* __restrict__ bgW, const float* __restrict__ bgate,
    const int* __restrict__ nptr, const int* __restrict__ ptrpos,
    float* __restrict__ out)
{
    const int lane = threadIdx.x & 63, wid = threadIdx.x >> 6;
    const int idx = blockIdx.x * 4 + wid;       // b*SS + m
    if (idx >= BB*SS) return;
    const int b = idx / SS, m = idx % SS;

    float s0, s1, s2;
    if (m < nptr[b]) {
        const int s = ptrpos[b*SS + m];
        const float4* c4 = (const float4*)(cls + (size_t)b * DD);
        float a0 = 0.f, a1 = 0.f, a2 = 0.f;
        #pragma unroll
        for (int j = 0; j < 3; ++j) {
            const float4 v = c4[j*64 + lane];
            const float* wp = WgW + ((size_t)s*DD + j*256 + lane*4) * 3;
            a0 += v.x*wp[0] + v.y*wp[3] + v.z*wp[6] + v.w*wp[9];
            a1 += v.x*wp[1] + v.y*wp[4] + v.z*wp[7] + v.w*wp[10];
            a2 += v.x*wp[2] + v.y*wp[5] + v.z*wp[8] + v.w*wp[11];
        }
        a0 = wred64(a0); a1 = wred64(a1); a2 = wred64(a2);
        s0 = a0 + bgW[s*3+0] + bgate[0];
        s1 = a1 + bgW[s*3+1] + bgate[1];
        s2 = a2 + bgW[s*3+2] + bgate[2];
    } else {
        s0 = bgate[0]; s1 = bgate[1]; s2 = bgate[2];
    }
    if (lane == 0) {
        const float mx = fmaxf(s0, fmaxf(s1, s2));
        const float e0 = expf(s0 - mx), e1 = expf(s1 - mx), e2 = expf(s2 - mx);
        const float inv = 1.f / (e0 + e1 + e2);
        float* o = out + O_GATE + (size_t)idx * NGATEc;
        o[0] = e0*inv; o[1] = e1*inv; o[2] = e2*inv;
    }
}

// ---------- Kernel E: softmax in place over L=512 ---------------------------
__global__ __launch_bounds__(256) void kE(
    const int* __restrict__ nsel, float* __restrict__ out)
{
    const int idx = blockIdx.x;             // b*SS + k
    const int b = idx / SS, k = idx % SS;
    const int tid = threadIdx.x;
    float* outs = out + O_SPROB + (size_t)idx * LL;
    float* oute = out + O_EPROB + (size_t)idx * LL;

    if (k >= nsel[b]) {                     // softmax(zeros) = 1/L exactly
        const float u = 1.0f / LL;
        outs[tid] = u; outs[tid + 256] = u;
        oute[tid] = u; oute[tid + 256] = u;
        return;
    }
    const int lane = tid & 63, wid = tid >> 6;
    __shared__ float rmax[2][4], rsum[2][4];

    const float s0 = outs[tid], s1 = outs[tid + 256];
    const float t0 = oute[tid], t1 = oute[tid + 256];

    float ms = fmaxf(s0, s1), me = fmaxf(t0, t1);
    #pragma unroll
    for (int o = 32; o; o >>= 1) { ms = fmaxf(ms, __shfl_xor(ms, o)); me = fmaxf(me, __shfl_xor(me, o)); }
    if (lane == 0) { rmax[0][wid] = ms; rmax[1][wid] = me; }
    __syncthreads();
    ms = fmaxf(fmaxf(rmax[0][0], rmax[0][1]), fmaxf(rmax[0][2], rmax[0][3]));
    me = fmaxf(fmaxf(rmax[1][0], rmax[1][1]), fmaxf(rmax[1][2], rmax[1][3]));

    const float e0 = expf(s0 - ms), e1 = expf(s1 - ms);
    const float f0 = expf(t0 - me), f1 = expf(t1 - me);
    float sa = e0 + e1, sb = f0 + f1;
    #pragma unroll
    for (int o = 32; o; o >>= 1) { sa += __shfl_xor(sa, o); sb += __shfl_xor(sb, o); }
    if (lane == 0) { rsum[0][wid] = sa; rsum[1][wid] = sb; }
    __syncthreads();
    const float inva = 1.f / (rsum[0][0] + rsum[0][1] + rsum[0][2] + rsum[0][3]);
    const float invb = 1.f / (rsum[1][0] + rsum[1][1] + rsum[1][2] + rsum[1][3]);

    outs[tid] = e0 * inva; outs[tid + 256] = e1 * inva;
    oute[tid] = f0 * invb; oute[tid + 256] = f1 * invb;
}

extern "C" void kernel_launch(void* const* d_in, const int* in_sizes, int n_in,
                              void* d_out, int out_size, void* d_ws, size_t ws_size,
                              hipStream_t stream)
{
    const float* H      = (const float*)d_in[0];
    const float* cls    = (const float*)d_in[1];
    const float* Wdom   = (const float*)d_in[2];
    const float* bdom   = (const float*)d_in[3];
    const float* Wslot  = (const float*)d_in[4];
    const float* bslot  = (const float*)d_in[5];
    const float* Wg     = (const float*)d_in[6];
    const float* bg     = (const float*)d_in[7];
    const float* Wgate  = (const float*)d_in[8];
    const float* bgate  = (const float*)d_in[9];
    const float* Wstart = (const float*)d_in[10];
    // d_in[11] b_start: constant per softmax row -> softmax-invariant, unused
    const float* Wend   = (const float*)d_in[12];
    // d_in[13] b_end: unused (same reason)
    const int* sp = (const int*)d_in[14];
    const int* sg = (const int*)d_in[15];

    float* out = (float*)d_out;
    float* wsf = (float*)d_ws;
    float* WgW = wsf + WS_WGW;
    float* bgW = wsf + WS_BGW;
    int* ipart  = (int*)(wsf + WS_INT);
    int* nptr   = ipart;
    int* nsel   = ipart + 64;
    int* ptrpos = ipart + 128;
    int* selpos = ptrpos + BB*SS;
    int* items  = selpos + BB*SS;
    int* NW     = items + MAXW;

    kA<<<BB, 256, 0, stream>>>(cls, Wdom, bdom, Wslot, bslot, sp, sg, out,
                               nptr, nsel, ptrpos, selpos);
    kA2<<<1, 64, 0, stream>>>(nsel, items, NW);
    kBD<<<GRID_BD, 256, 0, stream>>>(H, Wstart, Wend, nsel, selpos, out,
                                     Wg, bg, Wgate, WgW, bgW, items, NW);
    kC<<<(BB*SS) / 4, 256, 0, stream>>>(cls, WgW, bgW, bgate, nptr, ptrpos, out);
    kE<<<BB * SS, 256, 0, stream>>>(nsel, out);
}

// Round 14
// 78.693 us; speedup vs baseline: 1.2988x; 1.0113x over previous
//
#include <hip/hip_runtime.h>
#include <math.h>

// Problem constants (fixed by the reference setup)
constexpr int BB = 64, LL = 512, DD = 768, SS = 30;
constexpr int NDOMc = 5, NGATEc = 3, PRED = 2;

// Output layout (flat float32, reference return order)
constexpr size_t O_DOM   = 0;                               // (B,5)
constexpr size_t O_SPP   = O_DOM   + (size_t)BB*NDOMc;      // (B,30) sigmoid
constexpr size_t O_GATE  = O_SPP   + (size_t)BB*SS;         // (B,30,3) softmax
constexpr size_t O_SPTR  = O_GATE  + (size_t)BB*SS*NGATEc;  // (B,30) passthrough
constexpr size_t O_SGATE = O_SPTR  + (size_t)BB*SS;         // (B,30) passthrough
constexpr size_t O_SPROB = O_SGATE + (size_t)BB*SS;         // (B,30,512)
constexpr size_t O_EPROB = O_SPROB + (size_t)BB*SS*LL;      // (B,30,512)

// Workspace layout (floats): WgW[30*768*3], bgW[96], then ints
constexpr int WS_WGW = 0;
constexpr int WS_BGW = SS*DD*NGATEc;        // 69120
constexpr int WS_INT = WS_BGW + 96;         // 69216 (float offset where ints start)

constexpr int KB_ROWS = SS*DD + SS;         // 23070
constexpr int MAXW = 512;                   // max 4-slot items (worst case)
// Score block = (item w, 16-row chunk c): 32 chunks/item; grid covers w<256,
// with an in-kernel w+=256 wrap for the (never-in-practice) overflow case.
constexpr int SBLK = 256 * 32;              // 8192
constexpr int KB_BLOCKS = (KB_ROWS/2 + 3) / 4;            // 2884
constexpr int NGRP_S = (SBLK + 6) / 7;                    // 1171
constexpr int NGRP_K = (KB_BLOCKS + 4) / 5;               // 577
constexpr int NGRP = NGRP_S > NGRP_K ? NGRP_S : NGRP_K;   // 1171
constexpr int GRID_BD = NGRP * 12;          // 14052

__device__ __forceinline__ float wred64(float v) {
    #pragma unroll
    for (int o = 32; o; o >>= 1) v += __shfl_xor(v, o);
    return v;
}

// ---------- Kernel A: per-batch small dots, passthrough, scan/compaction ----
__global__ __launch_bounds__(256) void kA(
    const float* __restrict__ cls, const float* __restrict__ Wdom,
    const float* __restrict__ bdom, const float* __restrict__ Wslot,
    const float* __restrict__ bslot, const int* __restrict__ sp,
    const int* __restrict__ sg, float* __restrict__ out,
    int* __restrict__ nptr, int* __restrict__ nsel,
    int* __restrict__ ptrpos, int* __restrict__ selpos)
{
    const int b = blockIdx.x;
    const int tid = threadIdx.x, lane = tid & 63, wid = tid >> 6;
    const float* c = cls + (size_t)b * DD;

    for (int t = wid; t < NDOMc + SS; t += 4) {
        float acc = 0.f;
        if (t < NDOMc) {
            for (int d = lane; d < DD; d += 64) acc += c[d] * Wdom[d*NDOMc + t];
        } else {
            const int j = t - NDOMc;
            for (int d = lane; d < DD; d += 64) acc += c[d] * Wslot[d*SS + j];
        }
        acc = wred64(acc);
        if (lane == 0) {
            if (t < NDOMc) out[O_DOM + (size_t)b*NDOMc + t] = acc + bdom[t];
            else {
                const int j = t - NDOMc;
                const float x = acc + bslot[j];
                out[O_SPP + (size_t)b*SS + j] = 1.f / (1.f + expf(-x));
            }
        }
    }
    if (tid < SS) {
        out[O_SPTR  + (size_t)b*SS + tid] = (float)sp[b*SS + tid];
        out[O_SGATE + (size_t)b*SS + tid] = (float)sg[b*SS + tid];
    }
    // serial scan: ptr ranks and pmask compaction.
    // NOTE: gate_at_slot = slot_gate[b, clip(csum-1,0,M-1)] -> indexed by RANK.
    // selpos padded with the last valid slot so kBD stages UNCONDITIONALLY.
    if (tid == 0) {
        int cp = 0, cs = 0;
        for (int i = 0; i < SS; ++i) {
            if (sp[b*SS + i] == 1) {
                const int rank = cp;            // csum-1 at this position
                ptrpos[b*SS + rank] = i;
                ++cp;
                if (sg[b*SS + rank] == PRED) { selpos[b*SS + cs] = i; ++cs; }
            }
        }
        nptr[b] = cp; nsel[b] = cs;
        const int last = (cs > 0) ? selpos[b*SS + cs - 1] : 0;
        for (int i = cs; i < SS; ++i) selpos[b*SS + i] = last;
    }
}

// ---------- Kernel A2: compact (b, 4-slot group) work items, sorted by b ----
__global__ __launch_bounds__(64) void kA2(
    const int* __restrict__ nsel, int* __restrict__ items, int* __restrict__ NW)
{
    const int lane = threadIdx.x;               // 1 wave, lane == b
    const int ns = nsel[lane];
    const int cnt = (ns + 3) >> 2;              // ceil(ns/4) items
    int off = cnt;
    #pragma unroll
    for (int d = 1; d < 64; d <<= 1) {          // inclusive scan
        const int t = __shfl_up(off, d);
        if (lane >= d) off += t;
    }
    off -= cnt;                                 // exclusive prefix
    for (int i = 0; i < cnt; ++i) items[off + i] = lane * SS + 4*i;
    if (lane == 63) *NW = off + cnt;
}

// ---------- fused kBD: kB and score blocks INTERLEAVED (5:7 per 12) ---------
// Score block: 32-lane groups, 2 rows/thread (48 H VGPRs), 4-slot unrolled.
__global__ __launch_bounds__(256) void kBD(
    const float* __restrict__ H, const float* __restrict__ Ws,
    const float* __restrict__ We, const int* __restrict__ nsel,
    const int* __restrict__ selpos, float* __restrict__ out,
    const float* __restrict__ Wg, const float* __restrict__ bg,
    const float* __restrict__ Wgate,
    float* __restrict__ WgW, float* __restrict__ bgW,
    const int* __restrict__ items, const int* __restrict__ NW)
{
    __shared__ float4 wlds[1536];               // [slot 4][se 2][d4 192] = 24 KB
    const int bid = blockIdx.x;
    const int tid = threadIdx.x;
    const int g12 = bid / 12, r12 = bid % 12;

    if (r12 < 7) {
        const int sb = g12 * 7 + r12;
        if (sb >= SBLK) return;
        const int w0 = sb >> 5, c = sb & 31;    // consecutive sb share item w
        const int nw = *NW;
        for (int w = w0; w < nw; w += 256) {    // executes once for NW<=256
            const int item = items[w];
            const int b = item / SS, k0 = item % SS;
            const int ns = nsel[b];

            const int grp = tid >> 5, m = tid & 31; // 8 groups x 32 lanes
            const int l0 = c * 16 + grp * 2;        // rows l0, l0+1
            const int l1 = l0 + 1;

            // stage 4 slots' W_start/W_end unconditionally (selpos padded)
            #pragma unroll
            for (int t6 = 0; t6 < 6; ++t6) {
                const int idx = t6*256 + tid;       // 0..1535
                const int slot = idx / 384, rem = idx % 384;
                const int se = rem / 192, d4 = rem % 192;
                int kk = k0 + slot; if (kk > SS-1) kk = SS-1;
                const int s = selpos[b*SS + kk];
                const float4* src = (const float4*)((se ? We : Ws) + (size_t)s * DD);
                wlds[idx] = src[d4];
            }
            // H rows -> registers (24 floats/row/thread = 6 float4; 2 rows)
            const float4* h40 = (const float4*)(H + ((size_t)b * LL + l0) * DD);
            const float4* h41 = (const float4*)(H + ((size_t)b * LL + l1) * DD);
            float4 hr0[6], hr1[6];
            #pragma unroll
            for (int j = 0; j < 6; ++j) { hr0[j] = h40[j*32 + m]; hr1[j] = h41[j*32 + m]; }
            __syncthreads();

            #pragma unroll
            for (int t = 0; t < 4; ++t) {           // compile-time 4-slot unroll
                const float4* wls = wlds + t*384 + m;
                float a0=0.f, a1=0.f, e0=0.f, e1=0.f;
                #pragma unroll
                for (int j = 0; j < 6; ++j) {       // 2 ds_b128 : 16 fma
                    const float4 ww = wls[j*32];
                    const float4 uu = wls[192 + j*32];
                    a0 += hr0[j].x*ww.x + hr0[j].y*ww.y + hr0[j].z*ww.z + hr0[j].w*ww.w;
                    a1 += hr1[j].x*ww.x + hr1[j].y*ww.y + hr1[j].z*ww.z + hr1[j].w*ww.w;
                    e0 += hr0[j].x*uu.x + hr0[j].y*uu.y + hr0[j].z*uu.z + hr0[j].w*uu.w;
                    e1 += hr1[j].x*uu.x + hr1[j].y*uu.y + hr1[j].z*uu.z + hr1[j].w*uu.w;
                }
                #pragma unroll
                for (int o = 16; o; o >>= 1) {
                    a0 += __shfl_xor(a0, o); a1 += __shfl_xor(a1, o);
                    e0 += __shfl_xor(e0, o); e1 += __shfl_xor(e1, o);
                }
                const int ka = k0 + t;
                if (m == 0 && ka < ns) {
                    out[O_SPROB + (size_t)(b*SS + ka) * LL + l0] = a0;
                    out[O_SPROB + (size_t)(b*SS + ka) * LL + l1] = a1;
                    out[O_EPROB + (size_t)(b*SS + ka) * LL + l0] = e0;
                    out[O_EPROB + (size_t)(b*SS + ka) * LL + l1] = e1;
                }
            }
            if (w + 256 < nw) __syncthreads();      // wrap case only
        }
        return;
    }

    // ---- kB block: WgW precompute, 2 rows per wave; pure HBM stream --------
    const int kb = g12 * 5 + (r12 - 7);
    if (kb >= KB_BLOCKS) return;
    const int lane = tid & 63, wid = tid >> 6;
    const int r0 = (kb * 4 + wid) * 2;
    if (r0 >= KB_ROWS) return;

    float wgt[3][4][3];
    #pragma unroll
    for (int j = 0; j < 3; ++j)
        #pragma unroll
        for (int cc = 0; cc < 4; ++cc) {
            const int e = j*256 + lane*4 + cc;
            #pragma unroll
            for (int gg = 0; gg < NGATEc; ++gg) wgt[j][cc][gg] = Wgate[e*NGATEc + gg];
        }

    const float* src0 = (r0 < SS*DD) ? Wg + (size_t)r0*DD : bg + (size_t)(r0 - SS*DD)*DD;
    const int r1 = r0 + 1;
    const float* src1 = (r1 < SS*DD) ? Wg + (size_t)r1*DD : bg + (size_t)(r1 - SS*DD)*DD;
    float* dst0 = (r0 < SS*DD) ? WgW + (size_t)r0*3 : bgW + (r0 - SS*DD)*3;
    float* dst1 = (r1 < SS*DD) ? WgW + (size_t)r1*3 : bgW + (r1 - SS*DD)*3;

    const float4* s40 = (const float4*)src0;
    const float4* s41 = (const float4*)src1;
    float a0=0,a1=0,a2=0, c0=0,c1=0,c2=0;
    #pragma unroll
    for (int j = 0; j < 3; ++j) {
        const float4 v  = s40[j*64 + lane];
        const float4 w2 = s41[j*64 + lane];
        a0 += v.x*wgt[j][0][0] + v.y*wgt[j][1][0] + v.z*wgt[j][2][0] + v.w*wgt[j][3][0];
        a1 += v.x*wgt[j][0][1] + v.y*wgt[j][1][1] + v.z*wgt[j][2][1] + v.w*wgt[j][3][1];
        a2 += v.x*wgt[j][0][2] + v.y*wgt[j][1][2] + v.z*wgt[j][2][2] + v.w*wgt[j][3][2];
        c0 += w2.x*wgt[j][0][0] + w2.y*wgt[j][1][0] + w2.z*wgt[j][2][0] + w2.w*wgt[j][3][0];
        c1 += w2.x*wgt[j][0][1] + w2.y*wgt[j][1][1] + w2.z*wgt[j][2][1] + w2.w*wgt[j][3][1];
        c2 += w2.x*wgt[j][0][2] + w2.y*wgt[j][1][2] + w2.z*wgt[j][2][2] + w2.w*wgt[j][3][2];
    }
    a0 = wred64(a0); a1 = wred64(a1); a2 = wred64(a2);
    c0 = wred64(c0); c1 = wred64(c1); c2 = wred64(c2);
    if (lane == 0) {
        dst0[0] = a0; dst0[1] = a1; dst0[2] = a2;
        dst1[0] = c0; dst1[1] = c1; dst1[2] = c2;
    }
}

// ---------- Kernel C: slot_gate_prob ----------------------------------------
__global__ __launch_bounds__(256) void kC(
    const float* __restrict__ cls, const float* __restrict__ WgW,
    const float* __restrict__ bgW, const float* __restrict__ bgate,
    const int* __restrict__ nptr, const int* __restrict__ ptrpos,
    float* __restrict__ out)
{
    const int lane = threadIdx.x & 63, wid = threadIdx.x >> 6;
    const int idx = blockIdx.x * 4 + wid;       // b*SS + m
    if (idx >= BB*SS) return;
    const int b = idx / SS, m = idx % SS;

    float s0, s1, s2;
    if (m < nptr[b]) {
        const int s = ptrpos[b*SS + m];
        const float4* c4 = (const float4*)(cls + (size_t)b * DD);
        float a0 = 0.f, a1 = 0.f, a2 = 0.f;
        #pragma unroll
        for (int j = 0; j < 3; ++j) {
            const float4 v = c4[j*64 + lane];
            const float* wp = WgW + ((size_t)s*DD + j*256 + lane*4) * 3;
            a0 += v.x*wp[0] + v.y*wp[3] + v.z*wp[6] + v.w*wp[9];
            a1 += v.x*wp[1] + v.y*wp[4] + v.z*wp[7] + v.w*wp[10];
            a2 += v.x*wp[2] + v.y*wp[5] + v.z*wp[8] + v.w*wp[11];
        }
        a0 = wred64(a0); a1 = wred64(a1); a2 = wred64(a2);
        s0 = a0 + bgW[s*3+0] + bgate[0];
        s1 = a1 + bgW[s*3+1] + bgate[1];
        s2 = a2 + bgW[s*3+2] + bgate[2];
    } else {
        s0 = bgate[0]; s1 = bgate[1]; s2 = bgate[2];
    }
    if (lane == 0) {
        const float mx = fmaxf(s0, fmaxf(s1, s2));
        const float e0 = expf(s0 - mx), e1 = expf(s1 - mx), e2 = expf(s2 - mx);
        const float inv = 1.f / (e0 + e1 + e2);
        float* o = out + O_GATE + (size_t)idx * NGATEc;
        o[0] = e0*inv; o[1] = e1*inv; o[2] = e2*inv;
    }
}

// ---------- Kernel E: softmax in place over L=512 ---------------------------
__global__ __launch_bounds__(256) void kE(
    const int* __restrict__ nsel, float* __restrict__ out)
{
    const int idx = blockIdx.x;             // b*SS + k
    const int b = idx / SS, k = idx % SS;
    const int tid = threadIdx.x;
    float* outs = out + O_SPROB + (size_t)idx * LL;
    float* oute = out + O_EPROB + (size_t)idx * LL;

    if (k >= nsel[b]) {                     // softmax(zeros) = 1/L exactly
        const float u = 1.0f / LL;
        outs[tid] = u; outs[tid + 256] = u;
        oute[tid] = u; oute[tid + 256] = u;
        return;
    }
    const int lane = tid & 63, wid = tid >> 6;
    __shared__ float rmax[2][4], rsum[2][4];

    const float s0 = outs[tid], s1 = outs[tid + 256];
    const float t0 = oute[tid], t1 = oute[tid + 256];

    float ms = fmaxf(s0, s1), me = fmaxf(t0, t1);
    #pragma unroll
    for (int o = 32; o; o >>= 1) { ms = fmaxf(ms, __shfl_xor(ms, o)); me = fmaxf(me, __shfl_xor(me, o)); }
    if (lane == 0) { rmax[0][wid] = ms; rmax[1][wid] = me; }
    __syncthreads();
    ms = fmaxf(fmaxf(rmax[0][0], rmax[0][1]), fmaxf(rmax[0][2], rmax[0][3]));
    me = fmaxf(fmaxf(rmax[1][0], rmax[1][1]), fmaxf(rmax[1][2], rmax[1][3]));

    const float e0 = expf(s0 - ms), e1 = expf(s1 - ms);
    const float f0 = expf(t0 - me), f1 = expf(t1 - me);
    float sa = e0 + e1, sb = f0 + f1;
    #pragma unroll
    for (int o = 32; o; o >>= 1) { sa += __shfl_xor(sa, o); sb += __shfl_xor(sb, o); }
    if (lane == 0) { rsum[0][wid] = sa; rsum[1][wid] = sb; }
    __syncthreads();
    const float inva = 1.f / (rsum[0][0] + rsum[0][1] + rsum[0][2] + rsum[0][3]);
    const float invb = 1.f / (rsum[1][0] + rsum[1][1] + rsum[1][2] + rsum[1][3]);

    outs[tid] = e0 * inva; outs[tid + 256] = e1 * inva;
    oute[tid] = f0 * invb; oute[tid + 256] = f1 * invb;
}

extern "C" void kernel_launch(void* const* d_in, const int* in_sizes, int n_in,
                              void* d_out, int out_size, void* d_ws, size_t ws_size,
                              hipStream_t stream)
{
    const float* H      = (const float*)d_in[0];
    const float* cls    = (const float*)d_in[1];
    const float* Wdom   = (const float*)d_in[2];
    const float* bdom   = (const float*)d_in[3];
    const float* Wslot  = (const float*)d_in[4];
    const float* bslot  = (const float*)d_in[5];
    const float* Wg     = (const float*)d_in[6];
    const float* bg     = (const float*)d_in[7];
    const float* Wgate  = (const float*)d_in[8];
    const float* bgate  = (const float*)d_in[9];
    const float* Wstart = (const float*)d_in[10];
    // d_in[11] b_start: constant per softmax row -> softmax-invariant, unused
    const float* Wend   = (const float*)d_in[12];
    // d_in[13] b_end: unused (same reason)
    const int* sp = (const int*)d_in[14];
    const int* sg = (const int*)d_in[15];

    float* out = (float*)d_out;
    float* wsf = (float*)d_ws;
    float* WgW = wsf + WS_WGW;
    float* bgW = wsf + WS_BGW;
    int* ipart  = (int*)(wsf + WS_INT);
    int* nptr   = ipart;
    int* nsel   = ipart + 64;
    int* ptrpos = ipart + 128;
    int* selpos = ptrpos + BB*SS;
    int* items  = selpos + BB*SS;
    int* NW     = items + MAXW;

    kA<<<BB, 256, 0, stream>>>(cls, Wdom, bdom, Wslot, bslot, sp, sg, out,
                               nptr, nsel, ptrpos, selpos);
    kA2<<<1, 64, 0, stream>>>(nsel, items, NW);
    kBD<<<GRID_BD, 256, 0, stream>>>(H, Wstart, Wend, nsel, selpos, out,
                                     Wg, bg, Wgate, WgW, bgW, items, NW);
    kC<<<(BB*SS) / 4, 256, 0, stream>>>(cls, WgW, bgW, bgate, nptr, ptrpos, out);
    kE<<<BB * SS, 256, 0, stream>>>(nsel, out);
}

// Round 15
// 78.311 us; speedup vs baseline: 1.3051x; 1.0049x over previous
//
#include <hip/hip_runtime.h>
#include <math.h>

// Problem constants (fixed by the reference setup)
constexpr int BB = 64, LL = 512, DD = 768, SS = 30;
constexpr int NDOMc = 5, NGATEc = 3, PRED = 2;

// Output layout (flat float32, reference return order)
constexpr size_t O_DOM   = 0;                               // (B,5)
constexpr size_t O_SPP   = O_DOM   + (size_t)BB*NDOMc;      // (B,30) sigmoid
constexpr size_t O_GATE  = O_SPP   + (size_t)BB*SS;         // (B,30,3) softmax
constexpr size_t O_SPTR  = O_GATE  + (size_t)BB*SS*NGATEc;  // (B,30) passthrough
constexpr size_t O_SGATE = O_SPTR  + (size_t)BB*SS;         // (B,30) passthrough
constexpr size_t O_SPROB = O_SGATE + (size_t)BB*SS;         // (B,30,512)
constexpr size_t O_EPROB = O_SPROB + (size_t)BB*SS*LL;      // (B,30,512)

// Workspace layout (floats): WgW[30*768*3], bgW[96], then ints
constexpr int WS_WGW = 0;
constexpr int WS_BGW = SS*DD*NGATEc;        // 69120
constexpr int WS_INT = WS_BGW + 96;         // 69216 (float offset where ints start)

constexpr int KB_ROWS = SS*DD + SS;         // 23070
constexpr int MAXW = 512;                   // items buffer (worst case)
// Score block = (item w, 64-row EIGHTH e): W staged once per 4 compute iters.
constexpr int SBLK = 256 * 8;               // 2048 score slots (w<256 + wrap)
constexpr int KB_BLOCKS = (KB_ROWS/2 + 3) / 4;            // 2884
constexpr int NGRP_S = (SBLK + 1) / 2;                    // 1024
constexpr int NGRP_K = (KB_BLOCKS + 2) / 3;               // 962
constexpr int NGRP = NGRP_S > NGRP_K ? NGRP_S : NGRP_K;   // 1024
constexpr int GRID_BD = NGRP * 5;           // 5120 (2 score + 3 kB per 5)

__device__ __forceinline__ float wred64(float v) {
    #pragma unroll
    for (int o = 32; o; o >>= 1) v += __shfl_xor(v, o);
    return v;
}

// ---------- Kernel A: per-batch small dots, passthrough, scan/compaction ----
__global__ __launch_bounds__(256) void kA(
    const float* __restrict__ cls, const float* __restrict__ Wdom,
    const float* __restrict__ bdom, const float* __restrict__ Wslot,
    const float* __restrict__ bslot, const int* __restrict__ sp,
    const int* __restrict__ sg, float* __restrict__ out,
    int* __restrict__ nptr, int* __restrict__ nsel,
    int* __restrict__ ptrpos, int* __restrict__ selpos)
{
    const int b = blockIdx.x;
    const int tid = threadIdx.x, lane = tid & 63, wid = tid >> 6;
    const float* c = cls + (size_t)b * DD;

    for (int t = wid; t < NDOMc + SS; t += 4) {
        float acc = 0.f;
        if (t < NDOMc) {
            for (int d = lane; d < DD; d += 64) acc += c[d] * Wdom[d*NDOMc + t];
        } else {
            const int j = t - NDOMc;
            for (int d = lane; d < DD; d += 64) acc += c[d] * Wslot[d*SS + j];
        }
        acc = wred64(acc);
        if (lane == 0) {
            if (t < NDOMc) out[O_DOM + (size_t)b*NDOMc + t] = acc + bdom[t];
            else {
                const int j = t - NDOMc;
                const float x = acc + bslot[j];
                out[O_SPP + (size_t)b*SS + j] = 1.f / (1.f + expf(-x));
            }
        }
    }
    if (tid < SS) {
        out[O_SPTR  + (size_t)b*SS + tid] = (float)sp[b*SS + tid];
        out[O_SGATE + (size_t)b*SS + tid] = (float)sg[b*SS + tid];
    }
    // serial scan: ptr ranks and pmask compaction.
    // NOTE: gate_at_slot = slot_gate[b, clip(csum-1,0,M-1)] -> indexed by RANK.
    // selpos padded with the last valid slot so kBD stages UNCONDITIONALLY.
    if (tid == 0) {
        int cp = 0, cs = 0;
        for (int i = 0; i < SS; ++i) {
            if (sp[b*SS + i] == 1) {
                const int rank = cp;            // csum-1 at this position
                ptrpos[b*SS + rank] = i;
                ++cp;
                if (sg[b*SS + rank] == PRED) { selpos[b*SS + cs] = i; ++cs; }
            }
        }
        nptr[b] = cp; nsel[b] = cs;
        const int last = (cs > 0) ? selpos[b*SS + cs - 1] : 0;
        for (int i = cs; i < SS; ++i) selpos[b*SS + i] = last;
    }
}

// ---------- Kernel A2: compact (b, 4-slot group) work items, sorted by b ----
__global__ __launch_bounds__(64) void kA2(
    const int* __restrict__ nsel, int* __restrict__ items, int* __restrict__ NW)
{
    const int lane = threadIdx.x;               // 1 wave, lane == b
    const int ns = nsel[lane];
    const int cnt = (ns + 3) >> 2;              // ceil(ns/4) items
    int off = cnt;
    #pragma unroll
    for (int d = 1; d < 64; d <<= 1) {          // inclusive scan
        const int t = __shfl_up(off, d);
        if (lane >= d) off += t;
    }
    off -= cnt;                                 // exclusive prefix
    for (int i = 0; i < cnt; ++i) items[off + i] = lane * SS + 4*i;
    if (lane == 63) *NW = off + cnt;
}

// ---------- fused kBD: 2 score + 3 kB per 5 consecutive bids ---------------
// Score block: (item, 64-row eighth). Stage W once, 4 compute iterations.
__global__ __launch_bounds__(256) void kBD(
    const float* __restrict__ H, const float* __restrict__ Ws,
    const float* __restrict__ We, const int* __restrict__ nsel,
    const int* __restrict__ selpos, float* __restrict__ out,
    const float* __restrict__ Wg, const float* __restrict__ bg,
    const float* __restrict__ Wgate,
    float* __restrict__ WgW, float* __restrict__ bgW,
    const int* __restrict__ items, const int* __restrict__ NW)
{
    __shared__ float4 wlds[1536];               // [slot 4][se 2][d4 192] = 24 KB
    const int bid = blockIdx.x;
    const int tid = threadIdx.x;
    const int g5 = bid / 5, r5 = bid % 5;

    if (r5 < 2) {
        const int sb = g5 * 2 + r5;
        if (sb >= SBLK) return;
        const int w0 = sb >> 3, e = sb & 7;     // item, 64-row eighth
        const int nw = *NW;
        for (int w = w0; w < nw; w += 256) {    // executes once for NW<=256
            const int item = items[w];
            const int b = item / SS, k0 = item % SS;
            const int ns = nsel[b];

            // stage 4 slots' W_start/W_end unconditionally (selpos padded)
            #pragma unroll
            for (int t6 = 0; t6 < 6; ++t6) {
                const int idx = t6*256 + tid;       // 0..1535
                const int slot = idx / 384, rem = idx % 384;
                const int se = rem / 192, d4 = rem % 192;
                int kk = k0 + slot; if (kk > SS-1) kk = SS-1;
                const int s = selpos[b*SS + kk];
                const float4* src = (const float4*)((se ? We : Ws) + (size_t)s * DD);
                wlds[idx] = src[d4];
            }
            __syncthreads();

            const int grp = tid >> 5, m = tid & 31; // 8 groups x 32 lanes
            #pragma unroll
            for (int it = 0; it < 4; ++it) {        // 4 x 16 rows = 64 rows
                const int l0 = e * 64 + it * 16 + grp * 2;  // rows l0, l0+1
                const int l1 = l0 + 1;
                const float4* h40 = (const float4*)(H + ((size_t)b * LL + l0) * DD);
                const float4* h41 = (const float4*)(H + ((size_t)b * LL + l1) * DD);
                float4 hr0[6], hr1[6];
                #pragma unroll
                for (int j = 0; j < 6; ++j) { hr0[j] = h40[j*32 + m]; hr1[j] = h41[j*32 + m]; }

                #pragma unroll
                for (int t = 0; t < 4; ++t) {       // compile-time 4-slot unroll
                    const float4* wls = wlds + t*384 + m;
                    float a0=0.f, a1=0.f, e0=0.f, e1=0.f;
                    #pragma unroll
                    for (int j = 0; j < 6; ++j) {
                        const float4 ww = wls[j*32];
                        const float4 uu = wls[192 + j*32];
                        a0 += hr0[j].x*ww.x + hr0[j].y*ww.y + hr0[j].z*ww.z + hr0[j].w*ww.w;
                        a1 += hr1[j].x*ww.x + hr1[j].y*ww.y + hr1[j].z*ww.z + hr1[j].w*ww.w;
                        e0 += hr0[j].x*uu.x + hr0[j].y*uu.y + hr0[j].z*uu.z + hr0[j].w*uu.w;
                        e1 += hr1[j].x*uu.x + hr1[j].y*uu.y + hr1[j].z*uu.z + hr1[j].w*uu.w;
                    }
                    #pragma unroll
                    for (int o = 16; o; o >>= 1) {
                        a0 += __shfl_xor(a0, o); a1 += __shfl_xor(a1, o);
                        e0 += __shfl_xor(e0, o); e1 += __shfl_xor(e1, o);
                    }
                    const int ka = k0 + t;
                    if (m == 0 && ka < ns) {
                        out[O_SPROB + (size_t)(b*SS + ka) * LL + l0] = a0;
                        out[O_SPROB + (size_t)(b*SS + ka) * LL + l1] = a1;
                        out[O_EPROB + (size_t)(b*SS + ka) * LL + l0] = e0;
                        out[O_EPROB + (size_t)(b*SS + ka) * LL + l1] = e1;
                    }
                }
            }
            if (w + 256 < nw) __syncthreads();      // wrap case only
        }
        return;
    }

    // ---- kB block: WgW precompute, 2 rows per wave; pure HBM stream --------
    const int kb = g5 * 3 + (r5 - 2);
    if (kb >= KB_BLOCKS) return;
    const int lane = tid & 63, wid = tid >> 6;
    const int r0 = (kb * 4 + wid) * 2;
    if (r0 >= KB_ROWS) return;

    float wgt[3][4][3];
    #pragma unroll
    for (int j = 0; j < 3; ++j)
        #pragma unroll
        for (int cc = 0; cc < 4; ++cc) {
            const int e = j*256 + lane*4 + cc;
            #pragma unroll
            for (int gg = 0; gg < NGATEc; ++gg) wgt[j][cc][gg] = Wgate[e*NGATEc + gg];
        }

    const float* src0 = (r0 < SS*DD) ? Wg + (size_t)r0*DD : bg + (size_t)(r0 - SS*DD)*DD;
    const int r1 = r0 + 1;
    const float* src1 = (r1 < SS*DD) ? Wg + (size_t)r1*DD : bg + (size_t)(r1 - SS*DD)*DD;
    float* dst0 = (r0 < SS*DD) ? WgW + (size_t)r0*3 : bgW + (r0 - SS*DD)*3;
    float* dst1 = (r1 < SS*DD) ? WgW + (size_t)r1*3 : bgW + (r1 - SS*DD)*3;

    const float4* s40 = (const float4*)src0;
    const float4* s41 = (const float4*)src1;
    float a0=0,a1=0,a2=0, c0=0,c1=0,c2=0;
    #pragma unroll
    for (int j = 0; j < 3; ++j) {
        const float4 v  = s40[j*64 + lane];
        const float4 w2 = s41[j*64 + lane];
        a0 += v.x*wgt[j][0][0] + v.y*wgt[j][1][0] + v.z*wgt[j][2][0] + v.w*wgt[j][3][0];
        a1 += v.x*wgt[j][0][1] + v.y*wgt[j][1][1] + v.z*wgt[j][2][1] + v.w*wgt[j][3][1];
        a2 += v.x*wgt[j][0][2] + v.y*wgt[j][1][2] + v.z*wgt[j][2][2] + v.w*wgt[j][3][2];
        c0 += w2.x*wgt[j][0][0] + w2.y*wgt[j][1][0] + w2.z*wgt[j][2][0] + w2.w*wgt[j][3][0];
        c1 += w2.x*wgt[j][0][1] + w2.y*wgt[j][1][1] + w2.z*wgt[j][2][1] + w2.w*wgt[j][3][1];
        c2 += w2.x*wgt[j][0][2] + w2.y*wgt[j][1][2] + w2.z*wgt[j][2][2] + w2.w*wgt[j][3][2];
    }
    a0 = wred64(a0); a1 = wred64(a1); a2 = wred64(a2);
    c0 = wred64(c0); c1 = wred64(c1); c2 = wred64(c2);
    if (lane == 0) {
        dst0[0] = a0; dst0[1] = a1; dst0[2] = a2;
        dst1[0] = c0; dst1[1] = c1; dst1[2] = c2;
    }
}

// ---------- Kernel C: slot_gate_prob ----------------------------------------
__global__ __launch_bounds__(256) void kC(
    const float* __restrict__ cls, const float* __restrict__ WgW,
    const float* __restrict__ bgW, const float* __restrict__ bgate,
    const int* __restrict__ nptr, const int* __restrict__ ptrpos,
    float* __restrict__ out)
{
    const int lane = threadIdx.x & 63, wid = threadIdx.x >> 6;
    const int idx = blockIdx.x * 4 + wid;       // b*SS + m
    if (idx >= BB*SS) return;
    const int b = idx / SS, m = idx % SS;

    float s0, s1, s2;
    if (m < nptr[b]) {
        const int s = ptrpos[b*SS + m];
        const float4* c4 = (const float4*)(cls + (size_t)b * DD);
        float a0 = 0.f, a1 = 0.f, a2 = 0.f;
        #pragma unroll
        for (int j = 0; j < 3; ++j) {
            const float4 v = c4[j*64 + lane];
            const float* wp = WgW + ((size_t)s*DD + j*256 + lane*4) * 3;
            a0 += v.x*wp[0] + v.y*wp[3] + v.z*wp[6] + v.w*wp[9];
            a1 += v.x*wp[1] + v.y*wp[4] + v.z*wp[7] + v.w*wp[10];
            a2 += v.x*wp[2] + v.y*wp[5] + v.z*wp[8] + v.w*wp[11];
        }
        a0 = wred64(a0); a1 = wred64(a1); a2 = wred64(a2);
        s0 = a0 + bgW[s*3+0] + bgate[0];
        s1 = a1 + bgW[s*3+1] + bgate[1];
        s2 = a2 + bgW[s*3+2] + bgate[2];
    } else {
        s0 = bgate[0]; s1 = bgate[1]; s2 = bgate[2];
    }
    if (lane == 0) {
        const float mx = fmaxf(s0, fmaxf(s1, s2));
        const float e0 = expf(s0 - mx), e1 = expf(s1 - mx), e2 = expf(s2 - mx);
        const float inv = 1.f / (e0 + e1 + e2);
        float* o = out + O_GATE + (size_t)idx * NGATEc;
        o[0] = e0*inv; o[1] = e1*inv; o[2] = e2*inv;
    }
}

// ---------- Kernel E: softmax in place over L=512 ---------------------------
__global__ __launch_bounds__(256) void kE(
    const int* __restrict__ nsel, float* __restrict__ out)
{
    const int idx = blockIdx.x;             // b*SS + k
    const int b = idx / SS, k = idx % SS;
    const int tid = threadIdx.x;
    float* outs = out + O_SPROB + (size_t)idx * LL;
    float* oute = out + O_EPROB + (size_t)idx * LL;

    if (k >= nsel[b]) {                     // softmax(zeros) = 1/L exactly
        const float u = 1.0f / LL;
        outs[tid] = u; outs[tid + 256] = u;
        oute[tid] = u; oute[tid + 256] = u;
        return;
    }
    const int lane = tid & 63, wid = tid >> 6;
    __shared__ float rmax[2][4], rsum[2][4];

    const float s0 = outs[tid], s1 = outs[tid + 256];
    const float t0 = oute[tid], t1 = oute[tid + 256];

    float ms = fmaxf(s0, s1), me = fmaxf(t0, t1);
    #pragma unroll
    for (int o = 32; o; o >>= 1) { ms = fmaxf(ms, __shfl_xor(ms, o)); me = fmaxf(me, __shfl_xor(me, o)); }
    if (lane == 0) { rmax[0][wid] = ms; rmax[1][wid] = me; }
    __syncthreads();
    ms = fmaxf(fmaxf(rmax[0][0], rmax[0][1]), fmaxf(rmax[0][2], rmax[0][3]));
    me = fmaxf(fmaxf(rmax[1][0], rmax[1][1]), fmaxf(rmax[1][2], rmax[1][3]));

    const float e0 = expf(s0 - ms), e1 = expf(s1 - ms);
    const float f0 = expf(t0 - me), f1 = expf(t1 - me);
    float sa = e0 + e1, sb = f0 + f1;
    #pragma unroll
    for (int o = 32; o; o >>= 1) { sa += __shfl_xor(sa, o); sb += __shfl_xor(sb, o); }
    if (lane == 0) { rsum[0][wid] = sa; rsum[1][wid] = sb; }
    __syncthreads();
    const float inva = 1.f / (rsum[0][0] + rsum[0][1] + rsum[0][2] + rsum[0][3]);
    const float invb = 1.f / (rsum[1][0] + rsum[1][1] + rsum[1][2] + rsum[1][3]);

    outs[tid] = e0 * inva; outs[tid + 256] = e1 * inva;
    oute[tid] = f0 * invb; oute[tid + 256] = f1 * invb;
}

extern "C" void kernel_launch(void* const* d_in, const int* in_sizes, int n_in,
                              void* d_out, int out_size, void* d_ws, size_t ws_size,
                              hipStream_t stream)
{
    const float* H      = (const float*)d_in[0];
    const float* cls    = (const float*)d_in[1];
    const float* Wdom   = (const float*)d_in[2];
    const float* bdom   = (const float*)d_in[3];
    const float* Wslot  = (const float*)d_in[4];
    const float* bslot  = (const float*)d_in[5];
    const float* Wg     = (const float*)d_in[6];
    const float* bg     = (const float*)d_in[7];
    const float* Wgate  = (const float*)d_in[8];
    const float* bgate  = (const float*)d_in[9];
    const float* Wstart = (const float*)d_in[10];
    // d_in[11] b_start: constant per softmax row -> softmax-invariant, unused
    const float* Wend   = (const float*)d_in[12];
    // d_in[13] b_end: unused (same reason)
    const int* sp = (const int*)d_in[14];
    const int* sg = (const int*)d_in[15];

    float* out = (float*)d_out;
    float* wsf = (float*)d_ws;
    float* WgW = wsf + WS_WGW;
    float* bgW = wsf + WS_BGW;
    int* ipart  = (int*)(wsf + WS_INT);
    int* nptr   = ipart;
    int* nsel   = ipart + 64;
    int* ptrpos = ipart + 128;
    int* selpos = ptrpos + BB*SS;
    int* items  = selpos + BB*SS;
    int* NW     = items + MAXW;

    kA<<<BB, 256, 0, stream>>>(cls, Wdom, bdom, Wslot, bslot, sp, sg, out,
                               nptr, nsel, ptrpos, selpos);
    kA2<<<1, 64, 0, stream>>>(nsel, items, NW);
    kBD<<<GRID_BD, 256, 0, stream>>>(H, Wstart, Wend, nsel, selpos, out,
                                     Wg, bg, Wgate, WgW, bgW, items, NW);
    kC<<<(BB*SS) / 4, 256, 0, stream>>>(cls, WgW, bgW, bgate, nptr, ptrpos, out);
    kE<<<BB * SS, 256, 0, stream>>>(nsel, out);
}